// Round 8
// baseline (318.799 us; speedup 1.0000x reference)
//
#include <hip/hip_runtime.h>
#include <hip/hip_bf16.h>

#define NF 200
#define ND 32
#define NK 4
#define NH1 32
#define NH2 16
#define BN_EPS 1e-3f

// v + dpp_shuffled(v): all-VALU cross-lane add (no LDS pipe).
// CTRL: 0xB1 = quad_perm xor1, 0x4E = quad_perm xor2, 0x141 = row_half_mirror
// (xor 4 within 8), 0x128 = row_ror:8 (xor 8 within 16).
template<int CTRL>
__device__ __forceinline__ float dpp_add(float v) {
  const int r = __builtin_amdgcn_update_dpp(0, __float_as_int(v), CTRL, 0xF, 0xF, true);
  return v + __int_as_float(r);
}

typedef float vf4 __attribute__((ext_vector_type(4)));

// nontemporal 16B load: x is stream-once data, keep it out of L2 residency
__device__ __forceinline__ vf4 ntload4(const float* p) {
  return __builtin_nontemporal_load((const vf4*)p);
}

// One wave per batch row, 4 waves/block, 4 KB LDS/block.
// Stream: 5-deep rotating VGPR pipeline, fully unrolled (25 = 5 groups of 5,
// zero runtime branches between load issue and use). All in-loop reductions
// are DPP (VALU); weights/BN read from global (L2-resident, coalesced).
__global__ __launch_bounds__(256, 6) void mvke_fused(
    const float* __restrict__ x, const float* __restrict__ tag,
    const float* __restrict__ vk,
    const float* __restrict__ W1, const float* __restrict__ b1,
    const float* __restrict__ g1, const float* __restrict__ be1,
    const float* __restrict__ m1, const float* __restrict__ v1,
    const float* __restrict__ W2, const float* __restrict__ b2,
    const float* __restrict__ g2, const float* __restrict__ be2,
    const float* __restrict__ m2, const float* __restrict__ v2,
    float* __restrict__ out, int nrows)
{
  __shared__ float ctx_s[4][NK*ND];   // per-wave pooled context   (2 KB)
  __shared__ float h1_s[4][NK*NH1];   // per-wave tower-1 output   (2 KB)

  const int tid  = threadIdx.x;
  const int wave = tid >> 6;
  const int lane = tid & 63;
  const int fg   = lane >> 3;
  const int dl   = lane & 7;
  const int row  = blockIdx.x * 4 + wave;
  const bool live = (row < nrows);

  // vk transposed into registers: vkt[k][j] = vk[(4*dl+j), k]
  float vkt[NK][4];
  #pragma unroll
  for (int j = 0; j < 4; ++j) {
    const float4 vv = *(const float4*)(vk + (4*dl + j) * NK);
    vkt[0][j] = vv.x; vkt[1][j] = vv.y; vkt[2][j] = vv.z; vkt[3][j] = vv.w;
  }

  const float* xrow = x + (size_t)(live ? row : 0) * (NF*ND);
  const int laneoff = fg*ND + dl*4;

  float cx[NK], cy[NK], cz[NK], cw[NK], ls[NK];
  #pragma unroll
  for (int k = 0; k < NK; ++k) { cx[k]=cy[k]=cz[k]=cw[k]=ls[k]=0.f; }

  #define XLOAD(it) ntload4(xrow + (it)*(8*ND) + laneoff)
  #define PROCESS(xa)                                                         \
    {                                                                         \
      _Pragma("unroll")                                                       \
      for (int k = 0; k < NK; ++k) {                                          \
        float t = xa[0]*vkt[k][0] + xa[1]*vkt[k][1]                           \
                + xa[2]*vkt[k][2] + xa[3]*vkt[k][3];                          \
        t = dpp_add<0xB1>(t);                                                 \
        t = dpp_add<0x4E>(t);                                                 \
        t = dpp_add<0x141>(t);                                                \
        const float p = __expf(t);                                            \
        ls[k] += p;                                                           \
        cx[k] = fmaf(p, xa[0], cx[k]);                                        \
        cy[k] = fmaf(p, xa[1], cy[k]);                                        \
        cz[k] = fmaf(p, xa[2], cz[k]);                                        \
        cw[k] = fmaf(p, xa[3], cw[k]);                                        \
      }                                                                       \
    }

  // ---- stage 1: streaming pass, 5-deep pipeline, straight-line code ----
  {
    vf4 p0 = XLOAD(0), p1 = XLOAD(1), p2 = XLOAD(2), p3 = XLOAD(3),
        p4 = XLOAD(4);
    #pragma unroll
    for (int g = 0; g < 4; ++g) {          // tiles 0..19, refill 5..24
      const int base = (g + 1) * 5;
      { const vf4 cur = p0; p0 = XLOAD(base + 0); PROCESS(cur); }
      { const vf4 cur = p1; p1 = XLOAD(base + 1); PROCESS(cur); }
      { const vf4 cur = p2; p2 = XLOAD(base + 2); PROCESS(cur); }
      { const vf4 cur = p3; p3 = XLOAD(base + 3); PROCESS(cur); }
      { const vf4 cur = p4; p4 = XLOAD(base + 4); PROCESS(cur); }
    }
    PROCESS(p0); PROCESS(p1); PROCESS(p2); PROCESS(p3); PROCESS(p4); // 20..24
  }
  #undef PROCESS
  #undef XLOAD

  // ---- tail: combine the 8 f-groups (mask 8 via DPP, 16/32 via shfl) ----
  #pragma unroll
  for (int k = 0; k < NK; ++k) {
    ls[k] = dpp_add<0x128>(ls[k]);
    cx[k] = dpp_add<0x128>(cx[k]);
    cy[k] = dpp_add<0x128>(cy[k]);
    cz[k] = dpp_add<0x128>(cz[k]);
    cw[k] = dpp_add<0x128>(cw[k]);
    #pragma unroll
    for (int m = 16; m <= 32; m <<= 1) {
      ls[k] += __shfl_xor(ls[k], m);
      cx[k] += __shfl_xor(cx[k], m);
      cy[k] += __shfl_xor(cy[k], m);
      cz[k] += __shfl_xor(cz[k], m);
      cw[k] += __shfl_xor(cw[k], m);
    }
  }

  const float scale = 0.17677669529663687f;  // 1/sqrt(32)
  if (fg == 0) {
    #pragma unroll
    for (int k = 0; k < NK; ++k) {
      const float inv = scale / ls[k];
      float* p = &ctx_s[wave][k*ND + dl*4];
      p[0] = cx[k]*inv; p[1] = cy[k]*inv; p[2] = cz[k]*inv; p[3] = cw[k]*inv;
    }
  }
  __syncthreads();

  // ---- stage 2: tower 1 (Dense -> BN -> relu); weights from global/L2 ----
  #pragma unroll
  for (int rep = 0; rep < 2; ++rep) {
    const int o = lane + rep*64;
    const int k = o >> 5, h = o & 31;
    const float* wp = W1 + k*(ND*NH1) + h;
    const float* cp = &ctx_s[wave][k*ND];
    float acc = 0.f;
    #pragma unroll
    for (int d = 0; d < ND; ++d) acc = fmaf(cp[d], wp[d*NH1], acc);
    const float a = g1[o] * rsqrtf(v1[o] + BN_EPS);
    const float c = fmaf(b1[o] - m1[o], a, be1[o]);
    h1_s[wave][o] = fmaxf(fmaf(acc, a, c), 0.f);
  }
  __syncthreads();

  // ---- stage 3: tower 2 + gate + output ----
  {
    const int k3 = lane >> 4, j3 = lane & 15;
    const float* wp = W2 + k3*(NH1*NH2) + j3;
    const float* hp = &h1_s[wave][k3*NH1];
    float acc = 0.f;
    #pragma unroll
    for (int h = 0; h < NH1; ++h) acc = fmaf(hp[h], wp[h*NH2], acc);
    const int o = k3*NH2 + j3;
    const float a2 = g2[o] * rsqrtf(v2[o] + BN_EPS);
    const float c2 = fmaf(b2[o] - m2[o], a2, be2[o]);
    const float h2v = fmaxf(fmaf(acc, a2, c2), 0.f);

    // gate from tag embedding (redundant per lane; tag row is L1-hot)
    const float* tp = tag + (size_t)(live ? row : 0) * ND;
    float gs0=0.f, gs1=0.f, gs2=0.f, gs3=0.f;
    #pragma unroll
    for (int d = 0; d < ND; ++d) {
      const float t = tp[d];
      const float4 vv = *(const float4*)(vk + d*NK);
      gs0 = fmaf(t, vv.x, gs0);
      gs1 = fmaf(t, vv.y, gs1);
      gs2 = fmaf(t, vv.z, gs2);
      gs3 = fmaf(t, vv.w, gs3);
    }
    gs0 *= scale; gs1 *= scale; gs2 *= scale; gs3 *= scale;
    const float mx = fmaxf(fmaxf(gs0, gs1), fmaxf(gs2, gs3));
    const float e0 = __expf(gs0-mx), e1 = __expf(gs1-mx),
                e2 = __expf(gs2-mx), e3 = __expf(gs3-mx);
    const float esum = e0 + e1 + e2 + e3;
    const float ek = (k3 == 0) ? e0 : (k3 == 1) ? e1 : (k3 == 2) ? e2 : e3;

    float val = (ek / esum) * h2v;
    val += __shfl_xor(val, 16);
    val += __shfl_xor(val, 32);        // sum over the 4 experts
    if (live && lane < NH2) out[(size_t)row*NH2 + lane] = val;
  }
}

extern "C" void kernel_launch(void* const* d_in, const int* in_sizes, int n_in,
                              void* d_out, int out_size, void* d_ws, size_t ws_size,
                              hipStream_t stream) {
  const float* x   = (const float*)d_in[0];
  const float* tag = (const float*)d_in[1];
  const float* vk  = (const float*)d_in[2];
  const float* W1  = (const float*)d_in[3];
  const float* b1  = (const float*)d_in[4];
  const float* g1  = (const float*)d_in[5];
  const float* be1 = (const float*)d_in[6];
  const float* m1  = (const float*)d_in[7];
  const float* v1  = (const float*)d_in[8];
  const float* W2  = (const float*)d_in[9];
  const float* b2  = (const float*)d_in[10];
  const float* g2  = (const float*)d_in[11];
  const float* be2 = (const float*)d_in[12];
  const float* m2  = (const float*)d_in[13];
  const float* v2  = (const float*)d_in[14];
  float* out = (float*)d_out;

  const int nrows = in_sizes[1] / ND;          // B from tag_embedding
  const int nblocks = (nrows + 3) / 4;         // 4 waves/block, 1 row/wave
  mvke_fused<<<nblocks, 256, 0, stream>>>(x, tag, vk, W1, b1, g1, be1, m1, v1,
                                          W2, b2, g2, be2, m2, v2, out, nrows);
}

// Round 9
// 103.866 us; speedup vs baseline: 3.0693x; 3.0693x over previous
//
#include <hip/hip_runtime.h>
#include <hip/hip_bf16.h>

#define NF 200
#define ND 32
#define NK 4
#define NH1 32
#define NH2 16
#define BN_EPS 1e-3f

// v + dpp_shuffled(v): all-VALU cross-lane add (no LDS pipe).
// CTRL: 0xB1 = quad_perm xor1, 0x4E = quad_perm xor2, 0x141 = row_half_mirror
// (xor 4 within 8), 0x128 = row_ror:8 (xor 8 within 16).
template<int CTRL>
__device__ __forceinline__ float dpp_add(float v) {
  const int r = __builtin_amdgcn_update_dpp(0, __float_as_int(v), CTRL, 0xF, 0xF, true);
  return v + __int_as_float(r);
}

typedef float vf4 __attribute__((ext_vector_type(4)));

// nontemporal 16B load: x is stream-once data; bypass L2 residency churn
__device__ __forceinline__ vf4 ntload4(const float* p) {
  return __builtin_nontemporal_load((const vf4*)p);
}

// One wave per batch row, 4 waves/block, 4 KB LDS/block.
// Stream: 4-deep rotating VGPR pipeline in a RUNTIME group loop (do NOT
// fully unroll: straight-line 25-deep unrolls collapse the register
// allocator to 40 VGPR + scratch spill, measured R6/R8). All in-loop
// reductions are DPP (VALU); weights/BN read from global (L2-resident).
__global__ __launch_bounds__(256, 6) void mvke_fused(
    const float* __restrict__ x, const float* __restrict__ tag,
    const float* __restrict__ vk,
    const float* __restrict__ W1, const float* __restrict__ b1,
    const float* __restrict__ g1, const float* __restrict__ be1,
    const float* __restrict__ m1, const float* __restrict__ v1,
    const float* __restrict__ W2, const float* __restrict__ b2,
    const float* __restrict__ g2, const float* __restrict__ be2,
    const float* __restrict__ m2, const float* __restrict__ v2,
    float* __restrict__ out, int nrows)
{
  __shared__ float ctx_s[4][NK*ND];   // per-wave pooled context   (2 KB)
  __shared__ float h1_s[4][NK*NH1];   // per-wave tower-1 output   (2 KB)

  const int tid  = threadIdx.x;
  const int wave = tid >> 6;
  const int lane = tid & 63;
  const int fg   = lane >> 3;
  const int dl   = lane & 7;
  const int row  = blockIdx.x * 4 + wave;
  const bool live = (row < nrows);

  // vk transposed into registers: vkt[k][j] = vk[(4*dl+j), k]
  float vkt[NK][4];
  #pragma unroll
  for (int j = 0; j < 4; ++j) {
    const float4 vv = *(const float4*)(vk + (4*dl + j) * NK);
    vkt[0][j] = vv.x; vkt[1][j] = vv.y; vkt[2][j] = vv.z; vkt[3][j] = vv.w;
  }

  const float* xrow = x + (size_t)(live ? row : 0) * (NF*ND);
  const int laneoff = fg*ND + dl*4;

  float cx[NK], cy[NK], cz[NK], cw[NK], ls[NK];
  #pragma unroll
  for (int k = 0; k < NK; ++k) { cx[k]=cy[k]=cz[k]=cw[k]=ls[k]=0.f; }

  #define XLOAD(it) ntload4(xrow + (it)*(8*ND) + laneoff)
  #define PROCESS(xa)                                                         \
    {                                                                         \
      _Pragma("unroll")                                                       \
      for (int k = 0; k < NK; ++k) {                                          \
        float t = xa[0]*vkt[k][0] + xa[1]*vkt[k][1]                           \
                + xa[2]*vkt[k][2] + xa[3]*vkt[k][3];                          \
        t = dpp_add<0xB1>(t);                                                 \
        t = dpp_add<0x4E>(t);                                                 \
        t = dpp_add<0x141>(t);                                                \
        const float p = __expf(t);                                            \
        ls[k] += p;                                                           \
        cx[k] = fmaf(p, xa[0], cx[k]);                                        \
        cy[k] = fmaf(p, xa[1], cy[k]);                                        \
        cz[k] = fmaf(p, xa[2], cz[k]);                                        \
        cw[k] = fmaf(p, xa[3], cw[k]);                                        \
      }                                                                       \
    }

  // ---- stage 1: streaming pass, 4-deep rotating pipeline (R5 structure) ----
  {
    vf4 b0 = XLOAD(0), b1_ = XLOAD(1), b2_ = XLOAD(2), b3 = XLOAD(3);
    // iterations 0..23 in 6 groups of 4; 25th handled after
    for (int g = 0; g < 6; ++g) {
      const int base = g * 4;
      {
        const vf4 cur = b0;
        if (base + 4 < NF/8) b0 = XLOAD(base + 4);
        PROCESS(cur);
      }
      {
        const vf4 cur = b1_;
        if (base + 5 < NF/8) b1_ = XLOAD(base + 5);
        PROCESS(cur);
      }
      {
        const vf4 cur = b2_;
        if (base + 6 < NF/8) b2_ = XLOAD(base + 6);
        PROCESS(cur);
      }
      {
        const vf4 cur = b3;
        if (base + 7 < NF/8) b3 = XLOAD(base + 7);
        PROCESS(cur);
      }
    }
    PROCESS(b0);   // iteration 24
  }
  #undef PROCESS
  #undef XLOAD

  // ---- tail: combine the 8 f-groups (mask 8 via DPP, 16/32 via shfl) ----
  #pragma unroll
  for (int k = 0; k < NK; ++k) {
    ls[k] = dpp_add<0x128>(ls[k]);
    cx[k] = dpp_add<0x128>(cx[k]);
    cy[k] = dpp_add<0x128>(cy[k]);
    cz[k] = dpp_add<0x128>(cz[k]);
    cw[k] = dpp_add<0x128>(cw[k]);
    #pragma unroll
    for (int m = 16; m <= 32; m <<= 1) {
      ls[k] += __shfl_xor(ls[k], m);
      cx[k] += __shfl_xor(cx[k], m);
      cy[k] += __shfl_xor(cy[k], m);
      cz[k] += __shfl_xor(cz[k], m);
      cw[k] += __shfl_xor(cw[k], m);
    }
  }

  const float scale = 0.17677669529663687f;  // 1/sqrt(32)
  if (fg == 0) {
    #pragma unroll
    for (int k = 0; k < NK; ++k) {
      const float inv = scale / ls[k];
      float* p = &ctx_s[wave][k*ND + dl*4];
      p[0] = cx[k]*inv; p[1] = cy[k]*inv; p[2] = cz[k]*inv; p[3] = cw[k]*inv;
    }
  }
  __syncthreads();

  // ---- stage 2: tower 1 (Dense -> BN -> relu); weights from global/L2 ----
  #pragma unroll
  for (int rep = 0; rep < 2; ++rep) {
    const int o = lane + rep*64;
    const int k = o >> 5, h = o & 31;
    const float* wp = W1 + k*(ND*NH1) + h;
    const float* cp = &ctx_s[wave][k*ND];
    float acc = 0.f;
    #pragma unroll
    for (int d = 0; d < ND; ++d) acc = fmaf(cp[d], wp[d*NH1], acc);
    const float a = g1[o] * rsqrtf(v1[o] + BN_EPS);
    const float c = fmaf(b1[o] - m1[o], a, be1[o]);
    h1_s[wave][o] = fmaxf(fmaf(acc, a, c), 0.f);
  }
  __syncthreads();

  // ---- stage 3: tower 2 + gate + output ----
  {
    const int k3 = lane >> 4, j3 = lane & 15;
    const float* wp = W2 + k3*(NH1*NH2) + j3;
    const float* hp = &h1_s[wave][k3*NH1];
    float acc = 0.f;
    #pragma unroll
    for (int h = 0; h < NH1; ++h) acc = fmaf(hp[h], wp[h*NH2], acc);
    const int o = k3*NH2 + j3;
    const float a2 = g2[o] * rsqrtf(v2[o] + BN_EPS);
    const float c2 = fmaf(b2[o] - m2[o], a2, be2[o]);
    const float h2v = fmaxf(fmaf(acc, a2, c2), 0.f);

    // gate from tag embedding (redundant per lane; tag row is L1-hot)
    const float* tp = tag + (size_t)(live ? row : 0) * ND;
    float gs0=0.f, gs1=0.f, gs2=0.f, gs3=0.f;
    #pragma unroll
    for (int d = 0; d < ND; ++d) {
      const float t = tp[d];
      const float4 vv = *(const float4*)(vk + d*NK);
      gs0 = fmaf(t, vv.x, gs0);
      gs1 = fmaf(t, vv.y, gs1);
      gs2 = fmaf(t, vv.z, gs2);
      gs3 = fmaf(t, vv.w, gs3);
    }
    gs0 *= scale; gs1 *= scale; gs2 *= scale; gs3 *= scale;
    const float mx = fmaxf(fmaxf(gs0, gs1), fmaxf(gs2, gs3));
    const float e0 = __expf(gs0-mx), e1 = __expf(gs1-mx),
                e2 = __expf(gs2-mx), e3 = __expf(gs3-mx);
    const float esum = e0 + e1 + e2 + e3;
    const float ek = (k3 == 0) ? e0 : (k3 == 1) ? e1 : (k3 == 2) ? e2 : e3;

    float val = (ek / esum) * h2v;
    val += __shfl_xor(val, 16);
    val += __shfl_xor(val, 32);        // sum over the 4 experts
    if (live && lane < NH2) out[(size_t)row*NH2 + lane] = val;
  }
}

extern "C" void kernel_launch(void* const* d_in, const int* in_sizes, int n_in,
                              void* d_out, int out_size, void* d_ws, size_t ws_size,
                              hipStream_t stream) {
  const float* x   = (const float*)d_in[0];
  const float* tag = (const float*)d_in[1];
  const float* vk  = (const float*)d_in[2];
  const float* W1  = (const float*)d_in[3];
  const float* b1  = (const float*)d_in[4];
  const float* g1  = (const float*)d_in[5];
  const float* be1 = (const float*)d_in[6];
  const float* m1  = (const float*)d_in[7];
  const float* v1  = (const float*)d_in[8];
  const float* W2  = (const float*)d_in[9];
  const float* b2  = (const float*)d_in[10];
  const float* g2  = (const float*)d_in[11];
  const float* be2 = (const float*)d_in[12];
  const float* m2  = (const float*)d_in[13];
  const float* v2  = (const float*)d_in[14];
  float* out = (float*)d_out;

  const int nrows = in_sizes[1] / ND;          // B from tag_embedding
  const int nblocks = (nrows + 3) / 4;         // 4 waves/block, 1 row/wave
  mvke_fused<<<nblocks, 256, 0, stream>>>(x, tag, vk, W1, b1, g1, be1, m1, v1,
                                          W2, b2, g2, be2, m2, v2, out, nrows);
}